// Round 12
// baseline (82.966 us; speedup 1.0000x reference)
//
#include <hip/hip_runtime.h>
#include <hip/hip_bf16.h>

#define T_SEQ 2048
#define NH 16
#define HD 64
// 0.1 (attn scale) * log2(e) folded into q at norm time -> softmax uses exp2
#define SCALE_LOG2E 0.14426950408889634f

typedef __attribute__((ext_vector_type(8))) short bf16x8;
typedef __attribute__((ext_vector_type(4))) short bf16x4;
typedef __attribute__((ext_vector_type(4))) float f32x4;

__device__ __forceinline__ short f2bs(float f) {
  union { float f; unsigned u; } v; v.f = f;
  unsigned r = v.u + 0x7fffu + ((v.u >> 16) & 1u);
  return (short)(r >> 16);
}

__device__ __forceinline__ unsigned cvt_pk_bf16(float lo, float hi) {
  unsigned r;
  asm("v_cvt_pk_bf16_f32 %0, %1, %2" : "=v"(r) : "v"(lo), "v"(hi));
  return r;
}

__device__ __forceinline__ void gload16(const short* g, short* l) {
  __builtin_amdgcn_global_load_lds(
      (const __attribute__((address_space(1))) void*)g,
      (__attribute__((address_space(3))) void*)l, 16, 0, 0);
}

// -------- fused prep: transpose-convert (f32 row-major -> bf16 chunk-major [128][R][8]),
// v1 -> out[T*1024..] verbatim copy, and gate+rope plane (blockIdx.y==8).
__global__ __launch_bounds__(256) void prep(const float* __restrict__ x,
                                            const float* __restrict__ wq,
                                            const float* __restrict__ wk,
                                            const float* __restrict__ wv,
                                            const float* __restrict__ wp,
                                            const float* __restrict__ v1,
                                            const float* __restrict__ Wg,
                                            short* __restrict__ xbT,
                                            short* __restrict__ wqkvT,
                                            short* __restrict__ wpjT,
                                            float* __restrict__ out2,
                                            float* __restrict__ gate,
                                            float2* __restrict__ rope) {
  const int rt = blockIdx.x;   // 0..127
  const int tid = threadIdx.x;
  if (blockIdx.y == 8) {       // gate + rope plane: 128 blocks x 256 = 32768 ids
    int id = rt * 256 + tid;
    int t = id >> 4, h = id & 15;
    float acc = 0.f;
    #pragma unroll
    for (int i = 0; i < 12; ++i) acc += x[(size_t)t * 1024 + i] * Wg[h * 12 + i];
    gate[id] = 1.f / (1.f + __expf(-acc));
    #pragma unroll
    for (int j = 0; j < 2; ++j) {
      int e = id * 2 + j;
      int tt = e >> 5, p = e & 31;
      float invf = __builtin_exp2f(-0.41524101186092f * (float)p);
      float s, c;
      sincosf((float)tt * invf, &s, &c);
      rope[e] = make_float2(c, s);
    }
    return;
  }
  if (rt >= 96) {  // v1 -> out second half (f32 copy), 32 blocks x 8 col-slices
    const int r0 = (rt - 96) * 64;
    const float* s = v1 + (size_t)r0 * 1024 + blockIdx.y * 128;
    float* d = out2 + (size_t)r0 * 1024 + blockIdx.y * 128;
    #pragma unroll
    for (int it = 0; it < 8; ++it) {
      int e = it * 256 + tid;
      int r = e >> 5, c4 = e & 31;
      *(float4*)&d[(size_t)r * 1024 + c4 * 4] = *(const float4*)&s[(size_t)r * 1024 + c4 * 4];
    }
    return;
  }
  __shared__ __attribute__((aligned(16))) short lv[64][136];
  const float* src; short* dst; int srow0, drow0, R;
  if (rt < 32)      { src = x;  dst = xbT;   R = 2048; srow0 = rt * 64;        drow0 = srow0; }
  else if (rt < 48) { src = wq; dst = wqkvT; R = 3072; srow0 = (rt - 32) * 64; drow0 = srow0; }
  else if (rt < 64) { src = wk; dst = wqkvT; R = 3072; srow0 = (rt - 48) * 64; drow0 = srow0 + 1024; }
  else if (rt < 80) { src = wv; dst = wqkvT; R = 3072; srow0 = (rt - 64) * 64; drow0 = srow0 + 2048; }
  else              { src = wp; dst = wpjT;  R = 1024; srow0 = (rt - 80) * 64; drow0 = srow0; }
  const int c0 = blockIdx.y * 16;  // chunk base (cols k = blockIdx.y*128 ..+127)
  #pragma unroll
  for (int it = 0; it < 8; ++it) {
    int e = it * 256 + tid;
    int r = e >> 5, c4 = e & 31;
    float4 v = *(const float4*)&src[(size_t)(srow0 + r) * 1024 + blockIdx.y * 128 + c4 * 4];
    bf16x4 o; o[0] = f2bs(v.x); o[1] = f2bs(v.y); o[2] = f2bs(v.z); o[3] = f2bs(v.w);
    *(bf16x4*)&lv[r][c4 * 4] = o;
  }
  __syncthreads();
  #pragma unroll
  for (int it = 0; it < 4; ++it) {  // chunk-major, row fastest -> 1KB contiguous
    int e = it * 256 + tid;
    int kc = e >> 6, r = e & 63;
    bf16x8 w = *(const bf16x8*)&lv[r][kc * 8];
    *(bf16x8*)&dst[((size_t)(c0 + kc) * R + drow0 + r) * 8] = w;
  }
}

// ---------------- GEMM: BM x 128 tile, 4 waves, wave tile (BM/2)x64, BK=32,
// chunk-major operands, triple-buffer + counted vmcnt (never 0 in main loop).
// QKV=true (BM=128): fused epilogues -- q/k: RMSNorm+RoPE -> bf16 qb/kb;
// v: blend(v1,lamb) + permuted transpose via LDS union -> vt. QKV=false: f32 C.
template <int BM, bool QKV>
__global__ __launch_bounds__(256) void gemm(const short* __restrict__ A,
                                            const short* __restrict__ B,
                                            float* __restrict__ C,
                                            short* __restrict__ qb,
                                            short* __restrict__ kb,
                                            short* __restrict__ vt,
                                            const float* __restrict__ v1,
                                            const float* __restrict__ lambp,
                                            const float2* __restrict__ rope,
                                            int M, int N, int K) {
  constexpr int MF = BM / 32;      // M fragments per wave
  constexpr int LA = BM / 64;      // A gload16 per wave per step
  __shared__ union {
    struct { short As[3][4][BM][8]; short Bs[3][4][128][8]; } g;
    short lv[128][130];            // v-transpose tile (QKV only)
  } sm;
  const int tid = threadIdx.x;
  const int lane = tid & 63, wid = tid >> 6;
  const int lr = lane & 15, lg = lane >> 4;
  const int wm = (wid >> 1) * (BM / 2), wn = (wid & 1) * 64;
  const int bm = blockIdx.x * BM, bn = blockIdx.y * 128;
  const short* Ap = A + ((size_t)wid * M + bm + lane) * 8;
  const short* Bp = B + ((size_t)wid * N + bn + lane) * 8;
  f32x4 acc[MF][4] = {};
  auto stage = [&](int buf, int k0) {
    #pragma unroll
    for (int g = 0; g < LA; ++g)
      gload16(Ap + (size_t)k0 * M + g * 512, &sm.g.As[buf][wid][64 * g][0]);
    gload16(Bp + (size_t)k0 * N,       &sm.g.Bs[buf][wid][0][0]);
    gload16(Bp + (size_t)k0 * N + 512, &sm.g.Bs[buf][wid][64][0]);
  };
  auto compute = [&](int buf) {
    bf16x8 af[MF], bfr[4];
    #pragma unroll
    for (int m = 0; m < MF; ++m) af[m] = *(const bf16x8*)&sm.g.As[buf][lg][wm + m * 16 + lr][0];
    #pragma unroll
    for (int n = 0; n < 4; ++n) bfr[n] = *(const bf16x8*)&sm.g.Bs[buf][lg][wn + n * 16 + lr][0];
    #pragma unroll
    for (int m = 0; m < MF; ++m)
      #pragma unroll
      for (int n = 0; n < 4; ++n)
        acc[m][n] = __builtin_amdgcn_mfma_f32_16x16x32_bf16(af[m], bfr[n], acc[m][n], 0, 0, 0);
  };
  const int nsteps = K >> 5;
  stage(0, 0);
  stage(1, 32);
  int cur = 0;
  for (int ks = 0; ks < nsteps - 1; ++ks) {
    // wait only the oldest stage (LA+2 loads); next stage stays in flight
    if constexpr (BM == 128) asm volatile("s_waitcnt vmcnt(4)" ::: "memory");
    else                     asm volatile("s_waitcnt vmcnt(3)" ::: "memory");
    __builtin_amdgcn_s_barrier();
    __builtin_amdgcn_sched_barrier(0);
    int s2 = cur + 2; if (s2 >= 3) s2 -= 3;
    if (ks + 2 < nsteps) stage(s2, (ks + 2) * 32);
    compute(cur);
    cur = (cur == 2) ? 0 : cur + 1;
  }
  asm volatile("s_waitcnt vmcnt(0)" ::: "memory");
  __builtin_amdgcn_s_barrier();
  __builtin_amdgcn_sched_barrier(0);
  compute(cur);

  if constexpr (QKV) {
    if (bn < 2048) {  // q or k: wave cols = exactly one head
      const bool isq = (bn < 1024);
      short* dst = isq ? qb : kb;
      const int h = ((bn + wn) & 1023) >> 6;
      #pragma unroll
      for (int m = 0; m < MF; ++m)
        #pragma unroll
        for (int r = 0; r < 4; ++r) {
          const int t = bm + wm + m * 16 + 4 * lg + r;
          float ss = acc[m][0][r] * acc[m][0][r] + acc[m][1][r] * acc[m][1][r]
                   + acc[m][2][r] * acc[m][2][r] + acc[m][3][r] * acc[m][3][r];
          ss += __shfl_xor(ss, 1);
          ss += __shfl_xor(ss, 2);
          ss += __shfl_xor(ss, 4);
          ss += __shfl_xor(ss, 8);
          const float rms = rsqrtf(ss * (1.f / 64.f) + 1e-6f);
          short* row = dst + ((size_t)h * T_SEQ + t) * 64;
          #pragma unroll
          for (int n2 = 0; n2 < 2; ++n2) {  // rope pair (d, d+32) = frags (n2, n2+2)
            float x1 = acc[m][n2][r] * rms, x2 = acc[m][n2 + 2][r] * rms;
            float2 cs = rope[t * 32 + n2 * 16 + lr];
            float y1 = x1 * cs.x + x2 * cs.y;
            float y2 = x2 * cs.x - x1 * cs.y;
            if (isq) { y1 *= SCALE_LOG2E; y2 *= SCALE_LOG2E; }
            row[n2 * 16 + lr] = f2bs(y1);
            row[32 + n2 * 16 + lr] = f2bs(y2);
          }
        }
    } else {  // v: blend with v1, permuted transpose via LDS, write vt[h][d][t']
      const float Lb = *lambp;
      const int h0 = (bn - 2048) >> 6;  // block covers heads h0, h0+1
      __syncthreads();                  // all waves done reading As/Bs (union!)
      #pragma unroll
      for (int m = 0; m < MF; ++m)
        #pragma unroll
        for (int r = 0; r < 4; ++r) {
          const int tl = wm + m * 16 + 4 * lg + r;
          const size_t vrow = (size_t)(bm + tl) * 1024 + h0 * 64;
          #pragma unroll
          for (int n = 0; n < 4; ++n) {
            const int col = wn + n * 16 + lr;
            float w = v1[vrow + col];
            sm.lv[tl][col] = f2bs((1.f - Lb) * acc[m][n][r] + Lb * w);
          }
        }
      __syncthreads();
      // position c in each 32-block holds actual t-row (c&96)|((c&1)<<4)|((c>>1)&15)
      #pragma unroll
      for (int it = 0; it < 8; ++it) {
        int u = it * 256 + tid;
        int c0 = (u & 15) * 8;
        int d = (u >> 4) & 63;
        int hh = u >> 10;
        bf16x8 w;
        #pragma unroll
        for (int j = 0; j < 8; ++j) {
          int c = c0 + j;
          int src = (c & 96) | ((c & 1) << 4) | ((c >> 1) & 15);
          w[j] = sm.lv[src][hh * 64 + d];
        }
        *(bf16x8*)&vt[((size_t)(h0 + hh) * 64 + d) * T_SEQ + bm + c0] = w;
      }
    }
  } else {
    #pragma unroll
    for (int m = 0; m < MF; ++m)
      #pragma unroll
      for (int r = 0; r < 4; ++r) {
        const int t = bm + wm + m * 16 + 4 * lg + r;
        float* Cr = C + (size_t)t * N + bn + wn + lr;
        #pragma unroll
        for (int n = 0; n < 4; ++n) Cr[n * 16] = acc[m][n][r];
      }
  }
}

// ---------------- causal attention, one block per (head, qg), LPT heavy-first -------
// No split-KV: block b pairs with b+256 on the same CU to near-constant total work
// (qg 31..16 paired with 15..0). Gate + 1/lsum fused; writes chunk-major obT directly.
__global__ __launch_bounds__(256) void attn(const short* __restrict__ qb,
                                            const short* __restrict__ kb,
                                            const short* __restrict__ vtp,
                                            const float* __restrict__ gate,
                                            short* __restrict__ obT) {
  __shared__ __attribute__((aligned(16))) short Ks[2][4096];
  __shared__ __attribute__((aligned(16))) short Vs[2][4096];
  __shared__ __attribute__((aligned(16))) short p_lds[4][16][72];
  const int head = blockIdx.x & 15;
  const int qg = 31 - (blockIdx.x >> 4);  // heavy-first
  const int nt = qg + 1;
  const int lane = threadIdx.x & 63, wid = threadIdx.x >> 6;
  const int lr = lane & 15, lg = lane >> 4;
  const int qt0 = qg * 64 + wid * 16;
  const short* Q = qb + (size_t)head * (T_SEQ * HD);
  const short* Kp = kb + (size_t)head * (T_SEQ * HD);
  const short* Vt = vtp + (size_t)head * (HD * T_SEQ);
  short (*P)[72] = p_lds[wid];

  bf16x8 aq0 = *(const bf16x8*)&Q[(size_t)(qt0 + lr) * HD + 8 * lg];
  bf16x8 aq1 = *(const bf16x8*)&Q[(size_t)(qt0 + lr) * HD + 32 + 8 * lg];
  f32x4 accO[4] = {};
  float lsum[4] = {0.f, 0.f, 0.f, 0.f};

  auto stage = [&](int buf, int jg) {
    const int kv0 = jg * 64;
    #pragma unroll
    for (int i = 0; i < 2; ++i) {
      int s = i * 256 + wid * 64 + lane;
      int row = s >> 3;
      int cG = (s & 7) ^ (row & 7);  // inverse-swizzled source chunk
      gload16(Kp + (size_t)(kv0 + row) * HD + cG * 8,
              &Ks[buf][(size_t)(i * 256 + wid * 64) * 8]);
      gload16(Vt + (size_t)row * T_SEQ + kv0 + cG * 8,
              &Vs[buf][(size_t)(i * 256 + wid * 64) * 8]);
    }
  };
  stage(0, 0);
  for (int j = 0; j < nt; ++j) {
    __syncthreads();                          // drains vmcnt: buf[j&1] ready
    if (j + 1 < nt) stage((j + 1) & 1, j + 1);
    const short* Kb = Ks[j & 1];
    const short* Vb = Vs[j & 1];
    f32x4 st[4];
    #pragma unroll
    for (int t = 0; t < 4; ++t) {
      int row = 16 * t + lr;
      int c0 = lg ^ (row & 7);
      bf16x8 k0 = *(const bf16x8*)&Kb[row * 64 + c0 * 8];
      bf16x8 k1 = *(const bf16x8*)&Kb[row * 64 + (c0 ^ 4) * 8];
      f32x4 s = {};
      s = __builtin_amdgcn_mfma_f32_16x16x32_bf16(aq0, k0, s, 0, 0, 0);
      s = __builtin_amdgcn_mfma_f32_16x16x32_bf16(aq1, k1, s, 0, 0, 0);
      st[t] = s;
    }
    if (j == qg) {  // diagonal tile: causal mask (block-uniform branch)
      #pragma unroll
      for (int t = 0; t < 4; ++t)
        #pragma unroll
        for (int r = 0; r < 4; ++r)
          st[t][r] = (16 * t + lr > wid * 16 + 4 * lg + r) ? -1e30f : st[t][r];
    }
    #pragma unroll
    for (int r = 0; r < 4; ++r) {
      float p0 = __builtin_exp2f(st[0][r]);
      float p1 = __builtin_exp2f(st[1][r]);
      float p2 = __builtin_exp2f(st[2][r]);
      float p3 = __builtin_exp2f(st[3][r]);
      lsum[r] += (p0 + p1) + (p2 + p3);
      *(unsigned*)&P[4 * lg + r][2 * lr] = cvt_pk_bf16(p0, p1);
      *(unsigned*)&P[4 * lg + r][32 + 2 * lr] = cvt_pk_bf16(p2, p3);
    }
    asm volatile("s_waitcnt lgkmcnt(0)" ::: "memory");  // wave-private P roundtrip
    __builtin_amdgcn_sched_barrier(0);
    bf16x8 pa0 = *(const bf16x8*)&P[lr][8 * lg];
    bf16x8 pa1 = *(const bf16x8*)&P[lr][32 + 8 * lg];
    #pragma unroll
    for (int nv = 0; nv < 4; ++nv) {
      int row0 = nv * 16 + lr;
      int c0 = lg ^ (row0 & 7);
      bf16x8 v0 = *(const bf16x8*)&Vb[row0 * 64 + c0 * 8];
      bf16x8 v1e = *(const bf16x8*)&Vb[row0 * 64 + (c0 ^ 4) * 8];
      accO[nv] = __builtin_amdgcn_mfma_f32_16x16x32_bf16(pa0, v0, accO[nv], 0, 0, 0);
      accO[nv] = __builtin_amdgcn_mfma_f32_16x16x32_bf16(pa1, v1e, accO[nv], 0, 0, 0);
    }
  }
  // epilogue: gate/lsum, write chunk-major obT[cg][t][8] (proj A operand)
  #pragma unroll
  for (int r = 0; r < 4; ++r) {
    float sres = lsum[r];
    sres += __shfl_xor(sres, 1);
    sres += __shfl_xor(sres, 2);
    sres += __shfl_xor(sres, 4);
    sres += __shfl_xor(sres, 8);
    const int t = qt0 + 4 * lg + r;
    const float gs = gate[t * 16 + head] / sres;
    #pragma unroll
    for (int nv = 0; nv < 4; ++nv) {
      const int col = nv * 16 + lr;
      obT[((size_t)(head * 8 + (col >> 3)) * T_SEQ + t) * 8 + (col & 7)] =
          f2bs(accO[nv][r] * gs);
    }
  }
}

extern "C" void kernel_launch(void* const* d_in, const int* in_sizes, int n_in,
                              void* d_out, int out_size, void* d_ws, size_t ws_size,
                              hipStream_t stream) {
  const float* x     = (const float*)d_in[0];
  const float* v1    = (const float*)d_in[1];
  const float* Wq    = (const float*)d_in[2];
  const float* Wk    = (const float*)d_in[3];
  const float* Wv    = (const float*)d_in[4];
  const float* Wproj = (const float*)d_in[5];
  const float* lamb  = (const float*)d_in[6];
  const float* Wgate = (const float*)d_in[7];
  float* out = (float*)d_out;

  char* ws = (char*)d_ws;
  short*  xbT   = (short*)(ws);                       // 4MB chunk-major x (alias obT)
  short*  wqkvT = (short*)(ws + ((size_t)4  << 20));  // 6MB chunk-major Wq|Wk|Wv
  short*  wpjT  = (short*)(ws + ((size_t)10 << 20));  // 2MB chunk-major Wproj
  float2* rope  = (float2*)(ws + ((size_t)34 << 20)); // 512KB
  short*  qb    = (short*)(ws + ((size_t)36 << 20));  // 4MB
  short*  kb    = (short*)(ws + ((size_t)40 << 20));  // 4MB
  short*  vt    = (short*)(ws + ((size_t)44 << 20));  // 4MB
  float*  gate  = (float*)(ws + ((size_t)48 << 20));  // 128KB
  short*  obT   = xbT;  // xbT dead after QKV GEMM

  prep<<<dim3(128, 9), 256, 0, stream>>>(x, Wq, Wk, Wv, Wproj, v1, Wgate,
                                         xbT, wqkvT, wpjT,
                                         out + (size_t)T_SEQ * 1024, gate, rope);
  gemm<128, true><<<dim3(16, 24), 256, 0, stream>>>(xbT, wqkvT, nullptr, qb, kb, vt,
                                                    v1, lamb, rope, 2048, 3072, 1024);
  attn<<<512, 256, 0, stream>>>(qb, kb, vt, gate, obT);
  gemm<64, false><<<dim3(32, 8), 256, 0, stream>>>(obT, wpjT, out, nullptr, nullptr,
                                                   nullptr, nullptr, nullptr, nullptr,
                                                   2048, 1024, 1024);
}

// Round 13
// 75.696 us; speedup vs baseline: 1.0960x; 1.0960x over previous
//
#include <hip/hip_runtime.h>
#include <hip/hip_bf16.h>

#define T_SEQ 2048
#define NH 16
#define HD 64
// 0.1 (attn scale) * log2(e) folded into q at norm time -> softmax uses exp2
#define SCALE_LOG2E 0.14426950408889634f

typedef __attribute__((ext_vector_type(8))) short bf16x8;
typedef __attribute__((ext_vector_type(4))) short bf16x4;
typedef __attribute__((ext_vector_type(4))) float f32x4;

__device__ __forceinline__ short f2bs(float f) {
  union { float f; unsigned u; } v; v.f = f;
  unsigned r = v.u + 0x7fffu + ((v.u >> 16) & 1u);
  return (short)(r >> 16);
}

__device__ __forceinline__ float bs2f(short s) {
  union { unsigned u; float f; } v;
  v.u = ((unsigned)(unsigned short)s) << 16;
  return v.f;
}

__device__ __forceinline__ unsigned cvt_pk_bf16(float lo, float hi) {
  unsigned r;
  asm("v_cvt_pk_bf16_f32 %0, %1, %2" : "=v"(r) : "v"(lo), "v"(hi));
  return r;
}

__device__ __forceinline__ void gload16(const short* g, short* l) {
  __builtin_amdgcn_global_load_lds(
      (const __attribute__((address_space(1))) void*)g,
      (__attribute__((address_space(3))) void*)l, 16, 0, 0);
}

// -------- fused prep: transpose-convert (f32 row-major -> bf16 chunk-major [128][R][8]),
// v1 -> out[T*1024..] verbatim copy, and gate+rope plane (blockIdx.y==8).
__global__ __launch_bounds__(256) void prep(const float* __restrict__ x,
                                            const float* __restrict__ wq,
                                            const float* __restrict__ wk,
                                            const float* __restrict__ wv,
                                            const float* __restrict__ wp,
                                            const float* __restrict__ v1,
                                            const float* __restrict__ Wg,
                                            short* __restrict__ xbT,
                                            short* __restrict__ wqkvT,
                                            short* __restrict__ wpjT,
                                            float* __restrict__ out2,
                                            float* __restrict__ gate,
                                            float2* __restrict__ rope) {
  const int rt = blockIdx.x;   // 0..127
  const int tid = threadIdx.x;
  if (blockIdx.y == 8) {       // gate + rope plane: 128 blocks x 256 = 32768 ids
    int id = rt * 256 + tid;
    int t = id >> 4, h = id & 15;
    float acc = 0.f;
    #pragma unroll
    for (int i = 0; i < 12; ++i) acc += x[(size_t)t * 1024 + i] * Wg[h * 12 + i];
    gate[id] = 1.f / (1.f + __expf(-acc));
    #pragma unroll
    for (int j = 0; j < 2; ++j) {
      int e = id * 2 + j;
      int tt = e >> 5, p = e & 31;
      float invf = __builtin_exp2f(-0.41524101186092f * (float)p);
      float s, c;
      sincosf((float)tt * invf, &s, &c);
      rope[e] = make_float2(c, s);
    }
    return;
  }
  if (rt >= 96) {  // v1 -> out second half (f32 copy), 32 blocks x 8 col-slices
    const int r0 = (rt - 96) * 64;
    const float* s = v1 + (size_t)r0 * 1024 + blockIdx.y * 128;
    float* d = out2 + (size_t)r0 * 1024 + blockIdx.y * 128;
    #pragma unroll
    for (int it = 0; it < 8; ++it) {
      int e = it * 256 + tid;
      int r = e >> 5, c4 = e & 31;
      *(float4*)&d[(size_t)r * 1024 + c4 * 4] = *(const float4*)&s[(size_t)r * 1024 + c4 * 4];
    }
    return;
  }
  __shared__ __attribute__((aligned(16))) short lv[64][136];
  const float* src; short* dst; int srow0, drow0, R;
  if (rt < 32)      { src = x;  dst = xbT;   R = 2048; srow0 = rt * 64;        drow0 = srow0; }
  else if (rt < 48) { src = wq; dst = wqkvT; R = 3072; srow0 = (rt - 32) * 64; drow0 = srow0; }
  else if (rt < 64) { src = wk; dst = wqkvT; R = 3072; srow0 = (rt - 48) * 64; drow0 = srow0 + 1024; }
  else if (rt < 80) { src = wv; dst = wqkvT; R = 3072; srow0 = (rt - 64) * 64; drow0 = srow0 + 2048; }
  else              { src = wp; dst = wpjT;  R = 1024; srow0 = (rt - 80) * 64; drow0 = srow0; }
  const int c0 = blockIdx.y * 16;  // chunk base (cols k = blockIdx.y*128 ..+127)
  #pragma unroll
  for (int it = 0; it < 8; ++it) {
    int e = it * 256 + tid;
    int r = e >> 5, c4 = e & 31;
    float4 v = *(const float4*)&src[(size_t)(srow0 + r) * 1024 + blockIdx.y * 128 + c4 * 4];
    bf16x4 o; o[0] = f2bs(v.x); o[1] = f2bs(v.y); o[2] = f2bs(v.z); o[3] = f2bs(v.w);
    *(bf16x4*)&lv[r][c4 * 4] = o;
  }
  __syncthreads();
  #pragma unroll
  for (int it = 0; it < 4; ++it) {  // chunk-major, row fastest -> 1KB contiguous
    int e = it * 256 + tid;
    int kc = e >> 6, r = e & 63;
    bf16x8 w = *(const bf16x8*)&lv[r][kc * 8];
    *(bf16x8*)&dst[((size_t)(c0 + kc) * R + drow0 + r) * 8] = w;
  }
}

// ---------------- GEMM: BM x 128 tile, 4 waves, wave tile (BM/2)x64, BK=32,
// chunk-major operands, triple-buffer + counted vmcnt (never 0 in main loop).
// QKV=true (BM=128): fused epilogues -- q/k: RMSNorm+RoPE -> bf16 qb/kb;
// v: blend(v1,lamb) + permuted transpose via LDS union -> vt. QKV=false: f32 C.
template <int BM, bool QKV>
__global__ __launch_bounds__(256) void gemm(const short* __restrict__ A,
                                            const short* __restrict__ B,
                                            float* __restrict__ C,
                                            short* __restrict__ qb,
                                            short* __restrict__ kb,
                                            short* __restrict__ vt,
                                            const float* __restrict__ v1,
                                            const float* __restrict__ lambp,
                                            const float2* __restrict__ rope,
                                            int M, int N, int K) {
  constexpr int MF = BM / 32;      // M fragments per wave
  constexpr int LA = BM / 64;      // A gload16 per wave per step
  __shared__ union {
    struct { short As[3][4][BM][8]; short Bs[3][4][128][8]; } g;
    short lv[128][130];            // v-transpose tile (QKV only)
  } sm;
  const int tid = threadIdx.x;
  const int lane = tid & 63, wid = tid >> 6;
  const int lr = lane & 15, lg = lane >> 4;
  const int wm = (wid >> 1) * (BM / 2), wn = (wid & 1) * 64;
  const int bm = blockIdx.x * BM, bn = blockIdx.y * 128;
  const short* Ap = A + ((size_t)wid * M + bm + lane) * 8;
  const short* Bp = B + ((size_t)wid * N + bn + lane) * 8;
  f32x4 acc[MF][4] = {};
  auto stage = [&](int buf, int k0) {
    #pragma unroll
    for (int g = 0; g < LA; ++g)
      gload16(Ap + (size_t)k0 * M + g * 512, &sm.g.As[buf][wid][64 * g][0]);
    gload16(Bp + (size_t)k0 * N,       &sm.g.Bs[buf][wid][0][0]);
    gload16(Bp + (size_t)k0 * N + 512, &sm.g.Bs[buf][wid][64][0]);
  };
  auto compute = [&](int buf) {
    bf16x8 af[MF], bfr[4];
    #pragma unroll
    for (int m = 0; m < MF; ++m) af[m] = *(const bf16x8*)&sm.g.As[buf][lg][wm + m * 16 + lr][0];
    #pragma unroll
    for (int n = 0; n < 4; ++n) bfr[n] = *(const bf16x8*)&sm.g.Bs[buf][lg][wn + n * 16 + lr][0];
    #pragma unroll
    for (int m = 0; m < MF; ++m)
      #pragma unroll
      for (int n = 0; n < 4; ++n)
        acc[m][n] = __builtin_amdgcn_mfma_f32_16x16x32_bf16(af[m], bfr[n], acc[m][n], 0, 0, 0);
  };
  const int nsteps = K >> 5;
  stage(0, 0);
  stage(1, 32);
  int cur = 0;
  for (int ks = 0; ks < nsteps - 1; ++ks) {
    // wait only the oldest stage (LA+2 loads); next stage stays in flight
    if constexpr (BM == 128) asm volatile("s_waitcnt vmcnt(4)" ::: "memory");
    else                     asm volatile("s_waitcnt vmcnt(3)" ::: "memory");
    __builtin_amdgcn_s_barrier();
    __builtin_amdgcn_sched_barrier(0);
    int s2 = cur + 2; if (s2 >= 3) s2 -= 3;
    if (ks + 2 < nsteps) stage(s2, (ks + 2) * 32);
    compute(cur);
    cur = (cur == 2) ? 0 : cur + 1;
  }
  asm volatile("s_waitcnt vmcnt(0)" ::: "memory");
  __builtin_amdgcn_s_barrier();
  __builtin_amdgcn_sched_barrier(0);
  compute(cur);

  if constexpr (QKV) {
    if (bn < 2048) {  // q or k: wave cols = exactly one head
      const bool isq = (bn < 1024);
      short* dst = isq ? qb : kb;
      const int h = ((bn + wn) & 1023) >> 6;
      #pragma unroll
      for (int m = 0; m < MF; ++m)
        #pragma unroll
        for (int r = 0; r < 4; ++r) {
          const int t = bm + wm + m * 16 + 4 * lg + r;
          float ss = acc[m][0][r] * acc[m][0][r] + acc[m][1][r] * acc[m][1][r]
                   + acc[m][2][r] * acc[m][2][r] + acc[m][3][r] * acc[m][3][r];
          ss += __shfl_xor(ss, 1);
          ss += __shfl_xor(ss, 2);
          ss += __shfl_xor(ss, 4);
          ss += __shfl_xor(ss, 8);
          const float rms = rsqrtf(ss * (1.f / 64.f) + 1e-6f);
          short* row = dst + ((size_t)h * T_SEQ + t) * 64;
          #pragma unroll
          for (int n2 = 0; n2 < 2; ++n2) {  // rope pair (d, d+32) = frags (n2, n2+2)
            float x1 = acc[m][n2][r] * rms, x2 = acc[m][n2 + 2][r] * rms;
            float2 cs = rope[t * 32 + n2 * 16 + lr];
            float y1 = x1 * cs.x + x2 * cs.y;
            float y2 = x2 * cs.x - x1 * cs.y;
            if (isq) { y1 *= SCALE_LOG2E; y2 *= SCALE_LOG2E; }
            row[n2 * 16 + lr] = f2bs(y1);
            row[32 + n2 * 16 + lr] = f2bs(y2);
          }
        }
    } else {  // v: blend with v1, permuted transpose via LDS, write vt[h][d][t']
      const float Lb = *lambp;
      const int h0 = (bn - 2048) >> 6;  // block covers heads h0, h0+1
      __syncthreads();                  // all waves done reading As/Bs (union!)
      #pragma unroll
      for (int m = 0; m < MF; ++m)
        #pragma unroll
        for (int r = 0; r < 4; ++r) {
          const int tl = wm + m * 16 + 4 * lg + r;
          const size_t vrow = (size_t)(bm + tl) * 1024 + h0 * 64;
          #pragma unroll
          for (int n = 0; n < 4; ++n) {
            const int col = wn + n * 16 + lr;
            float w = v1[vrow + col];
            sm.lv[tl][col] = f2bs((1.f - Lb) * acc[m][n][r] + Lb * w);
          }
        }
      __syncthreads();
      // position c in each 32-block holds actual t-row (c&96)|((c&1)<<4)|((c>>1)&15)
      #pragma unroll
      for (int it = 0; it < 8; ++it) {
        int u = it * 256 + tid;
        int c0 = (u & 15) * 8;
        int d = (u >> 4) & 63;
        int hh = u >> 10;
        bf16x8 w;
        #pragma unroll
        for (int j = 0; j < 8; ++j) {
          int c = c0 + j;
          int src = (c & 96) | ((c & 1) << 4) | ((c >> 1) & 15);
          w[j] = sm.lv[src][hh * 64 + d];
        }
        *(bf16x8*)&vt[((size_t)(h0 + hh) * 64 + d) * T_SEQ + bm + c0] = w;
      }
    }
  } else {
    #pragma unroll
    for (int m = 0; m < MF; ++m)
      #pragma unroll
      for (int r = 0; r < 4; ++r) {
        const int t = bm + wm + m * 16 + 4 * lg + r;
        float* Cr = C + (size_t)t * N + bn + wn + lr;
        #pragma unroll
        for (int n = 0; n < 4; ++n) Cr[n * 16] = acc[m][n][r];
      }
  }
}

// ---------------- causal attention, split-KV (restored from round 11) ----------------
// 1280 near-uniform blocks (~5/CU, ~20 waves/CU): latency chains hidden by TLP.
// Partials: bf16 O + f32 lsum, compact slot = head*80 + b.
__global__ __launch_bounds__(256) void attn(const short* __restrict__ qb,
                                            const short* __restrict__ kb,
                                            const short* __restrict__ vtp,
                                            short* __restrict__ partO,
                                            float* __restrict__ partL) {
  __shared__ __attribute__((aligned(16))) short Ks[2][4096];
  __shared__ __attribute__((aligned(16))) short Vs[2][4096];
  __shared__ __attribute__((aligned(16))) short p_lds[4][16][72];
  const int head = blockIdx.x & 15;
  const int b = blockIdx.x >> 4;  // 0..79
  int strip, qg;  // heavy-first within each strip class
  if (b < 32)      { strip = 0; qg = 31 - b; }
  else if (b < 56) { strip = 1; qg = 63 - b; }
  else if (b < 72) { strip = 2; qg = 87 - b; }
  else             { strip = 3; qg = 103 - b; }
  const int nt = min(8, qg + 1 - strip * 8);
  const int lane = threadIdx.x & 63, wid = threadIdx.x >> 6;
  const int lr = lane & 15, lg = lane >> 4;
  const int qt0 = qg * 64 + wid * 16;
  const short* Q = qb + (size_t)head * (T_SEQ * HD);
  const short* Kp = kb + (size_t)head * (T_SEQ * HD);
  const short* Vt = vtp + (size_t)head * (HD * T_SEQ);
  short (*P)[72] = p_lds[wid];

  bf16x8 aq0 = *(const bf16x8*)&Q[(size_t)(qt0 + lr) * HD + 8 * lg];
  bf16x8 aq1 = *(const bf16x8*)&Q[(size_t)(qt0 + lr) * HD + 32 + 8 * lg];
  f32x4 accO[4] = {};
  float lsum[4] = {0.f, 0.f, 0.f, 0.f};

  auto stage = [&](int buf, int jg) {
    const int kv0 = jg * 64;
    #pragma unroll
    for (int i = 0; i < 2; ++i) {
      int s = i * 256 + wid * 64 + lane;
      int row = s >> 3;
      int cG = (s & 7) ^ (row & 7);  // inverse-swizzled source chunk
      gload16(Kp + (size_t)(kv0 + row) * HD + cG * 8,
              &Ks[buf][(size_t)(i * 256 + wid * 64) * 8]);
      gload16(Vt + (size_t)row * T_SEQ + kv0 + cG * 8,
              &Vs[buf][(size_t)(i * 256 + wid * 64) * 8]);
    }
  };
  stage(0, strip * 8);
  for (int j = 0; j < nt; ++j) {
    const int jg = strip * 8 + j;
    __syncthreads();
    if (j + 1 < nt) stage((j + 1) & 1, jg + 1);
    const short* Kb = Ks[j & 1];
    const short* Vb = Vs[j & 1];
    f32x4 st[4];
    #pragma unroll
    for (int t = 0; t < 4; ++t) {
      int row = 16 * t + lr;
      int c0 = lg ^ (row & 7);
      bf16x8 k0 = *(const bf16x8*)&Kb[row * 64 + c0 * 8];
      bf16x8 k1 = *(const bf16x8*)&Kb[row * 64 + (c0 ^ 4) * 8];
      f32x4 s = {};
      s = __builtin_amdgcn_mfma_f32_16x16x32_bf16(aq0, k0, s, 0, 0, 0);
      s = __builtin_amdgcn_mfma_f32_16x16x32_bf16(aq1, k1, s, 0, 0, 0);
      st[t] = s;
    }
    if (jg == qg) {
      #pragma unroll
      for (int t = 0; t < 4; ++t)
        #pragma unroll
        for (int r = 0; r < 4; ++r)
          st[t][r] = (16 * t + lr > wid * 16 + 4 * lg + r) ? -1e30f : st[t][r];
    }
    #pragma unroll
    for (int r = 0; r < 4; ++r) {
      float p0 = __builtin_exp2f(st[0][r]);
      float p1 = __builtin_exp2f(st[1][r]);
      float p2 = __builtin_exp2f(st[2][r]);
      float p3 = __builtin_exp2f(st[3][r]);
      lsum[r] += (p0 + p1) + (p2 + p3);
      *(unsigned*)&P[4 * lg + r][2 * lr] = cvt_pk_bf16(p0, p1);
      *(unsigned*)&P[4 * lg + r][32 + 2 * lr] = cvt_pk_bf16(p2, p3);
    }
    asm volatile("s_waitcnt lgkmcnt(0)" ::: "memory");
    __builtin_amdgcn_sched_barrier(0);
    bf16x8 pa0 = *(const bf16x8*)&P[lr][8 * lg];
    bf16x8 pa1 = *(const bf16x8*)&P[lr][32 + 8 * lg];
    #pragma unroll
    for (int nv = 0; nv < 4; ++nv) {
      int row0 = nv * 16 + lr;
      int c0 = lg ^ (row0 & 7);
      bf16x8 v0 = *(const bf16x8*)&Vb[row0 * 64 + c0 * 8];
      bf16x8 v1e = *(const bf16x8*)&Vb[row0 * 64 + (c0 ^ 4) * 8];
      accO[nv] = __builtin_amdgcn_mfma_f32_16x16x32_bf16(pa0, v0, accO[nv], 0, 0, 0);
      accO[nv] = __builtin_amdgcn_mfma_f32_16x16x32_bf16(pa1, v1e, accO[nv], 0, 0, 0);
    }
  }
  short* pO = partO + (size_t)(head * 80 + b) * 4096;
  float* pL = partL + (size_t)(head * 80 + b) * 64;
  #pragma unroll
  for (int r = 0; r < 4; ++r) {
    float sres = lsum[r];
    sres += __shfl_xor(sres, 1);
    sres += __shfl_xor(sres, 2);
    sres += __shfl_xor(sres, 4);
    sres += __shfl_xor(sres, 8);
    int row = wid * 16 + 4 * lg + r;
    #pragma unroll
    for (int nv = 0; nv < 4; ++nv)
      pO[row * 64 + nv * 16 + lr] = f2bs(accO[nv][r]);
    if (lr == 0) pL[row] = sres;
  }
}

// ------- combine split-KV partials, apply gate, write CHUNK-MAJOR bf16 obT[128][2048][8]
__global__ __launch_bounds__(256) void attn_reduce(const short* __restrict__ partO,
                                                   const float* __restrict__ partL,
                                                   const float* __restrict__ gate,
                                                   short* __restrict__ obT) {
  const int head = blockIdx.x & 15;
  const int qg = blockIdx.x >> 4;
  const int ns = (qg >> 3) + 1;
  const int tid = threadIdx.x;
  const int row = tid >> 2, q4 = tid & 3;
  const int sbase[4] = {0, 32, 56, 72};  // strip -> b base (b = sbase[s] + 31 - qg)
  f32x4 o[4] = {};
  float l = 0.f;
  for (int s = 0; s < ns; ++s) {
    const int slot = head * 80 + sbase[s] + 31 - qg;
    const short* pb = partO + (size_t)slot * 4096;
    #pragma unroll
    for (int c = 0; c < 4; ++c) {
      bf16x4 v = *(const bf16x4*)&pb[row * 64 + q4 * 16 + c * 4];
      #pragma unroll
      for (int j = 0; j < 4; ++j) o[c][j] += bs2f(v[j]);
    }
    l += partL[(size_t)slot * 64 + row];
  }
  const int t = qg * 64 + row;
  const float gs = gate[t * 16 + head] / l;
  const int cg0 = head * 8 + q4 * 2;
  bf16x8 w0, w1;
  #pragma unroll
  for (int j = 0; j < 4; ++j) {
    w0[j]     = f2bs(o[0][j] * gs);
    w0[4 + j] = f2bs(o[1][j] * gs);
    w1[j]     = f2bs(o[2][j] * gs);
    w1[4 + j] = f2bs(o[3][j] * gs);
  }
  *(bf16x8*)&obT[((size_t)cg0 * 2048 + t) * 8] = w0;
  *(bf16x8*)&obT[((size_t)(cg0 + 1) * 2048 + t) * 8] = w1;
}

extern "C" void kernel_launch(void* const* d_in, const int* in_sizes, int n_in,
                              void* d_out, int out_size, void* d_ws, size_t ws_size,
                              hipStream_t stream) {
  const float* x     = (const float*)d_in[0];
  const float* v1    = (const float*)d_in[1];
  const float* Wq    = (const float*)d_in[2];
  const float* Wk    = (const float*)d_in[3];
  const float* Wv    = (const float*)d_in[4];
  const float* Wproj = (const float*)d_in[5];
  const float* lamb  = (const float*)d_in[6];
  const float* Wgate = (const float*)d_in[7];
  float* out = (float*)d_out;

  char* ws = (char*)d_ws;
  short*  xbT   = (short*)(ws);                       // 4MB chunk-major x (alias obT)
  short*  wqkvT = (short*)(ws + ((size_t)4  << 20));  // 6MB chunk-major Wq|Wk|Wv
  short*  wpjT  = (short*)(ws + ((size_t)10 << 20));  // 2MB chunk-major Wproj
  short*  partO = (short*)(ws + ((size_t)12 << 20));  // 10.5MB bf16 O partials
  float*  partL = (float*)(ws + ((size_t)23 << 20));  // 327KB f32 lsum partials
  float2* rope  = (float2*)(ws + ((size_t)34 << 20)); // 512KB
  short*  qb    = (short*)(ws + ((size_t)36 << 20));  // 4MB
  short*  kb    = (short*)(ws + ((size_t)40 << 20));  // 4MB
  short*  vt    = (short*)(ws + ((size_t)44 << 20));  // 4MB
  float*  gate  = (float*)(ws + ((size_t)48 << 20));  // 128KB
  short*  obT   = xbT;  // xbT dead after QKV GEMM

  prep<<<dim3(128, 9), 256, 0, stream>>>(x, Wq, Wk, Wv, Wproj, v1, Wgate,
                                         xbT, wqkvT, wpjT,
                                         out + (size_t)T_SEQ * 1024, gate, rope);
  gemm<128, true><<<dim3(16, 24), 256, 0, stream>>>(xbT, wqkvT, nullptr, qb, kb, vt,
                                                    v1, lamb, rope, 2048, 3072, 1024);
  attn<<<1280, 256, 0, stream>>>(qb, kb, vt, partO, partL);
  attn_reduce<<<512, 256, 0, stream>>>(partO, partL, gate, obT);
  gemm<64, false><<<dim3(32, 8), 256, 0, stream>>>(obT, wpjT, out, nullptr, nullptr,
                                                   nullptr, nullptr, nullptr, nullptr,
                                                   2048, 1024, 1024);
}

// Round 14
// 73.306 us; speedup vs baseline: 1.1318x; 1.0326x over previous
//
#include <hip/hip_runtime.h>
#include <hip/hip_bf16.h>

#define T_SEQ 2048
#define NH 16
#define HD 64
// 0.1 (attn scale) * log2(e) folded into q at norm time -> softmax uses exp2
#define SCALE_LOG2E 0.14426950408889634f

typedef __attribute__((ext_vector_type(8))) short bf16x8;
typedef __attribute__((ext_vector_type(4))) short bf16x4;
typedef __attribute__((ext_vector_type(4))) float f32x4;

__device__ __forceinline__ short f2bs(float f) {
  union { float f; unsigned u; } v; v.f = f;
  unsigned r = v.u + 0x7fffu + ((v.u >> 16) & 1u);
  return (short)(r >> 16);
}

__device__ __forceinline__ float bs2f(short s) {
  union { unsigned u; float f; } v;
  v.u = ((unsigned)(unsigned short)s) << 16;
  return v.f;
}

__device__ __forceinline__ unsigned cvt_pk_bf16(float lo, float hi) {
  unsigned r;
  asm("v_cvt_pk_bf16_f32 %0, %1, %2" : "=v"(r) : "v"(lo), "v"(hi));
  return r;
}

__device__ __forceinline__ void gload16(const short* g, short* l) {
  __builtin_amdgcn_global_load_lds(
      (const __attribute__((address_space(1))) void*)g,
      (__attribute__((address_space(3))) void*)l, 16, 0, 0);
}

// -------- fused prep: transpose-convert (f32 row-major -> bf16 chunk-major [128][R][8]),
// v1 -> out[T*1024..] verbatim copy, and gate+rope plane (blockIdx.y==8).
__global__ __launch_bounds__(256) void prep(const float* __restrict__ x,
                                            const float* __restrict__ wq,
                                            const float* __restrict__ wk,
                                            const float* __restrict__ wv,
                                            const float* __restrict__ wp,
                                            const float* __restrict__ v1,
                                            const float* __restrict__ Wg,
                                            short* __restrict__ xbT,
                                            short* __restrict__ wqkvT,
                                            short* __restrict__ wpjT,
                                            float* __restrict__ out2,
                                            float* __restrict__ gate,
                                            float2* __restrict__ rope) {
  const int rt = blockIdx.x;   // 0..127
  const int tid = threadIdx.x;
  if (blockIdx.y == 8) {       // gate + rope plane
    int id = rt * 256 + tid;
    int t = id >> 4, h = id & 15;
    float acc = 0.f;
    #pragma unroll
    for (int i = 0; i < 12; ++i) acc += x[(size_t)t * 1024 + i] * Wg[h * 12 + i];
    gate[id] = 1.f / (1.f + __expf(-acc));
    #pragma unroll
    for (int j = 0; j < 2; ++j) {
      int e = id * 2 + j;
      int tt = e >> 5, p = e & 31;
      float invf = __builtin_exp2f(-0.41524101186092f * (float)p);
      float s, c;
      sincosf((float)tt * invf, &s, &c);
      rope[e] = make_float2(c, s);
    }
    return;
  }
  if (rt >= 96) {  // v1 -> out second half (f32 copy)
    const int r0 = (rt - 96) * 64;
    const float* s = v1 + (size_t)r0 * 1024 + blockIdx.y * 128;
    float* d = out2 + (size_t)r0 * 1024 + blockIdx.y * 128;
    #pragma unroll
    for (int it = 0; it < 8; ++it) {
      int e = it * 256 + tid;
      int r = e >> 5, c4 = e & 31;
      *(float4*)&d[(size_t)r * 1024 + c4 * 4] = *(const float4*)&s[(size_t)r * 1024 + c4 * 4];
    }
    return;
  }
  __shared__ __attribute__((aligned(16))) short lv[64][136];
  const float* src; short* dst; int srow0, drow0, R;
  if (rt < 32)      { src = x;  dst = xbT;   R = 2048; srow0 = rt * 64;        drow0 = srow0; }
  else if (rt < 48) { src = wq; dst = wqkvT; R = 3072; srow0 = (rt - 32) * 64; drow0 = srow0; }
  else if (rt < 64) { src = wk; dst = wqkvT; R = 3072; srow0 = (rt - 48) * 64; drow0 = srow0 + 1024; }
  else if (rt < 80) { src = wv; dst = wqkvT; R = 3072; srow0 = (rt - 64) * 64; drow0 = srow0 + 2048; }
  else              { src = wp; dst = wpjT;  R = 1024; srow0 = (rt - 80) * 64; drow0 = srow0; }
  const int c0 = blockIdx.y * 16;  // chunk base (cols k = blockIdx.y*128 ..+127)
  #pragma unroll
  for (int it = 0; it < 8; ++it) {
    int e = it * 256 + tid;
    int r = e >> 5, c4 = e & 31;
    float4 v = *(const float4*)&src[(size_t)(srow0 + r) * 1024 + blockIdx.y * 128 + c4 * 4];
    bf16x4 o; o[0] = f2bs(v.x); o[1] = f2bs(v.y); o[2] = f2bs(v.z); o[3] = f2bs(v.w);
    *(bf16x4*)&lv[r][c4 * 4] = o;
  }
  __syncthreads();
  #pragma unroll
  for (int it = 0; it < 4; ++it) {  // chunk-major, row fastest -> 1KB contiguous
    int e = it * 256 + tid;
    int kc = e >> 6, r = e & 63;
    bf16x8 w = *(const bf16x8*)&lv[r][kc * 8];
    *(bf16x8*)&dst[((size_t)(c0 + kc) * R + drow0 + r) * 8] = w;
  }
}

// ---------------- GEMM: BM x BN tile, 4 waves, wave tile (BM/2)x(BN/2), BK=32,
// chunk-major operands, triple-buffer + counted vmcnt (never 0 in main loop).
// 1D grid with XCD-chunked bijective swizzle (grid%8==0): each XCD owns a contiguous
// by-major tile range -> B panels stay in one XCD's L2 (T1).
// QKV=true (BN=128): fused epilogues -- q/k: RMSNorm+RoPE -> bf16 qb/kb;
// v: blend(v1,lamb) + permuted transpose via LDS union -> vt. QKV=false: f32 C.
template <int BM, int BN, bool QKV>
__global__ __launch_bounds__(256) void gemm(const short* __restrict__ A,
                                            const short* __restrict__ B,
                                            float* __restrict__ C,
                                            short* __restrict__ qb,
                                            short* __restrict__ kb,
                                            short* __restrict__ vt,
                                            const float* __restrict__ v1,
                                            const float* __restrict__ lambp,
                                            const float2* __restrict__ rope,
                                            int M, int N, int K) {
  constexpr int MF = BM / 32, NB = BN / 32;   // fragments per wave
  constexpr int LA = BM / 64, LB = BN / 64;   // gload16 per wave per step
  __shared__ union {
    struct { short As[3][4][BM][8]; short Bs[3][4][BN][8]; } g;
    short lv[BM][130];            // v-transpose tile (QKV only)
  } sm;
  const int tid = threadIdx.x;
  const int lane = tid & 63, wid = tid >> 6;
  const int lr = lane & 15, lg = lane >> 4;
  const int wm = (wid >> 1) * (BM / 2), wn = (wid & 1) * (BN / 2);
  // XCD-chunked swizzle: bid%8 = XCD; each XCD gets a contiguous by-major range
  const int nper = gridDim.x >> 3;
  const int tile = (blockIdx.x & 7) * nper + (blockIdx.x >> 3);
  const int gx = M / BM;
  const int bm = (tile % gx) * BM, bn = (tile / gx) * BN;
  const short* Ap = A + ((size_t)wid * M + bm + lane) * 8;
  const short* Bp = B + ((size_t)wid * N + bn + lane) * 8;
  f32x4 acc[MF][NB] = {};
  auto stage = [&](int buf, int k0) {
    #pragma unroll
    for (int g = 0; g < LA; ++g)
      gload16(Ap + (size_t)k0 * M + g * 512, &sm.g.As[buf][wid][64 * g][0]);
    #pragma unroll
    for (int g = 0; g < LB; ++g)
      gload16(Bp + (size_t)k0 * N + g * 512, &sm.g.Bs[buf][wid][64 * g][0]);
  };
  auto compute = [&](int buf) {
    bf16x8 af[MF], bfr[NB];
    #pragma unroll
    for (int m = 0; m < MF; ++m) af[m] = *(const bf16x8*)&sm.g.As[buf][lg][wm + m * 16 + lr][0];
    #pragma unroll
    for (int n = 0; n < NB; ++n) bfr[n] = *(const bf16x8*)&sm.g.Bs[buf][lg][wn + n * 16 + lr][0];
    #pragma unroll
    for (int m = 0; m < MF; ++m)
      #pragma unroll
      for (int n = 0; n < NB; ++n)
        acc[m][n] = __builtin_amdgcn_mfma_f32_16x16x32_bf16(af[m], bfr[n], acc[m][n], 0, 0, 0);
  };
  const int nsteps = K >> 5;
  stage(0, 0);
  stage(1, 32);
  int cur = 0;
  for (int ks = 0; ks < nsteps - 1; ++ks) {
    // wait only the oldest stage (LA+LB loads); next stage stays in flight
    if constexpr (LA + LB == 4)      asm volatile("s_waitcnt vmcnt(4)" ::: "memory");
    else if constexpr (LA + LB == 3) asm volatile("s_waitcnt vmcnt(3)" ::: "memory");
    else                             asm volatile("s_waitcnt vmcnt(2)" ::: "memory");
    __builtin_amdgcn_s_barrier();
    __builtin_amdgcn_sched_barrier(0);
    int s2 = cur + 2; if (s2 >= 3) s2 -= 3;
    if (ks + 2 < nsteps) stage(s2, (ks + 2) * 32);
    compute(cur);
    cur = (cur == 2) ? 0 : cur + 1;
  }
  asm volatile("s_waitcnt vmcnt(0)" ::: "memory");
  __builtin_amdgcn_s_barrier();
  __builtin_amdgcn_sched_barrier(0);
  compute(cur);

  if constexpr (QKV) {
    if (bn < 2048) {  // q or k: wave cols = exactly one head (BN=128, NB=4)
      const bool isq = (bn < 1024);
      short* dst = isq ? qb : kb;
      const int h = ((bn + wn) & 1023) >> 6;
      #pragma unroll
      for (int m = 0; m < MF; ++m)
        #pragma unroll
        for (int r = 0; r < 4; ++r) {
          const int t = bm + wm + m * 16 + 4 * lg + r;
          float ss = acc[m][0][r] * acc[m][0][r] + acc[m][1][r] * acc[m][1][r]
                   + acc[m][2][r] * acc[m][2][r] + acc[m][3][r] * acc[m][3][r];
          ss += __shfl_xor(ss, 1);
          ss += __shfl_xor(ss, 2);
          ss += __shfl_xor(ss, 4);
          ss += __shfl_xor(ss, 8);
          const float rms = rsqrtf(ss * (1.f / 64.f) + 1e-6f);
          short* row = dst + ((size_t)h * T_SEQ + t) * 64;
          #pragma unroll
          for (int n2 = 0; n2 < 2; ++n2) {  // rope pair (d, d+32) = frags (n2, n2+2)
            float x1 = acc[m][n2][r] * rms, x2 = acc[m][n2 + 2][r] * rms;
            float2 cs = rope[t * 32 + n2 * 16 + lr];
            float y1 = x1 * cs.x + x2 * cs.y;
            float y2 = x2 * cs.x - x1 * cs.y;
            if (isq) { y1 *= SCALE_LOG2E; y2 *= SCALE_LOG2E; }
            row[n2 * 16 + lr] = f2bs(y1);
            row[32 + n2 * 16 + lr] = f2bs(y2);
          }
        }
    } else {  // v: blend with v1, permuted transpose via LDS, write vt[h][d][t']
      const float Lb = *lambp;
      const int h0 = (bn - 2048) >> 6;  // block covers heads h0, h0+1
      __syncthreads();                  // all waves done reading As/Bs (union!)
      #pragma unroll
      for (int m = 0; m < MF; ++m)
        #pragma unroll
        for (int r = 0; r < 4; ++r) {
          const int tl = wm + m * 16 + 4 * lg + r;
          const size_t vrow = (size_t)(bm + tl) * 1024 + h0 * 64;
          #pragma unroll
          for (int n = 0; n < NB; ++n) {
            const int col = wn + n * 16 + lr;
            float w = v1[vrow + col];
            sm.lv[tl][col] = f2bs((1.f - Lb) * acc[m][n][r] + Lb * w);
          }
        }
      __syncthreads();
      // position c in each 32-block holds actual t-row (c&96)|((c&1)<<4)|((c>>1)&15)
      constexpr int TPB = BM / 8;       // bf16x8 chunks per (hh,d) row
      #pragma unroll
      for (int it = 0; it < BM / 16; ++it) {
        int u = it * 256 + tid;         // u in [0, 16*BM)
        int c0 = (u % TPB) * 8;
        int d = (u / TPB) & 63;
        int hh = u / (TPB * 64);
        bf16x8 w;
        #pragma unroll
        for (int j = 0; j < 8; ++j) {
          int c = c0 + j;
          int src = (c & 96) | ((c & 1) << 4) | ((c >> 1) & 15);
          w[j] = sm.lv[src][hh * 64 + d];
        }
        *(bf16x8*)&vt[((size_t)(h0 + hh) * 64 + d) * T_SEQ + bm + c0] = w;
      }
    }
  } else {
    #pragma unroll
    for (int m = 0; m < MF; ++m)
      #pragma unroll
      for (int r = 0; r < 4; ++r) {
        const int t = bm + wm + m * 16 + 4 * lg + r;
        float* Cr = C + (size_t)t * N + bn + wn + lr;
        #pragma unroll
        for (int n = 0; n < NB; ++n) Cr[n * 16] = acc[m][n][r];
      }
  }
}

// ---------------- causal attention, split-KV ----------------
// 1280 near-uniform blocks (~5/CU, ~20 waves/CU): latency chains hidden by TLP.
// Partials: bf16 O + f32 lsum, compact slot = head*80 + b.
__global__ __launch_bounds__(256) void attn(const short* __restrict__ qb,
                                            const short* __restrict__ kb,
                                            const short* __restrict__ vtp,
                                            short* __restrict__ partO,
                                            float* __restrict__ partL) {
  __shared__ __attribute__((aligned(16))) short Ks[2][4096];
  __shared__ __attribute__((aligned(16))) short Vs[2][4096];
  __shared__ __attribute__((aligned(16))) short p_lds[4][16][72];
  const int head = blockIdx.x & 15;
  const int b = blockIdx.x >> 4;  // 0..79
  int strip, qg;  // heavy-first within each strip class
  if (b < 32)      { strip = 0; qg = 31 - b; }
  else if (b < 56) { strip = 1; qg = 63 - b; }
  else if (b < 72) { strip = 2; qg = 87 - b; }
  else             { strip = 3; qg = 103 - b; }
  const int nt = min(8, qg + 1 - strip * 8);
  const int lane = threadIdx.x & 63, wid = threadIdx.x >> 6;
  const int lr = lane & 15, lg = lane >> 4;
  const int qt0 = qg * 64 + wid * 16;
  const short* Q = qb + (size_t)head * (T_SEQ * HD);
  const short* Kp = kb + (size_t)head * (T_SEQ * HD);
  const short* Vt = vtp + (size_t)head * (HD * T_SEQ);
  short (*P)[72] = p_lds[wid];

  bf16x8 aq0 = *(const bf16x8*)&Q[(size_t)(qt0 + lr) * HD + 8 * lg];
  bf16x8 aq1 = *(const bf16x8*)&Q[(size_t)(qt0 + lr) * HD + 32 + 8 * lg];
  f32x4 accO[4] = {};
  float lsum[4] = {0.f, 0.f, 0.f, 0.f};

  auto stage = [&](int buf, int jg) {
    const int kv0 = jg * 64;
    #pragma unroll
    for (int i = 0; i < 2; ++i) {
      int s = i * 256 + wid * 64 + lane;
      int row = s >> 3;
      int cG = (s & 7) ^ (row & 7);  // inverse-swizzled source chunk
      gload16(Kp + (size_t)(kv0 + row) * HD + cG * 8,
              &Ks[buf][(size_t)(i * 256 + wid * 64) * 8]);
      gload16(Vt + (size_t)row * T_SEQ + kv0 + cG * 8,
              &Vs[buf][(size_t)(i * 256 + wid * 64) * 8]);
    }
  };
  stage(0, strip * 8);
  for (int j = 0; j < nt; ++j) {
    const int jg = strip * 8 + j;
    __syncthreads();
    if (j + 1 < nt) stage((j + 1) & 1, jg + 1);
    const short* Kb = Ks[j & 1];
    const short* Vb = Vs[j & 1];
    f32x4 st[4];
    #pragma unroll
    for (int t = 0; t < 4; ++t) {
      int row = 16 * t + lr;
      int c0 = lg ^ (row & 7);
      bf16x8 k0 = *(const bf16x8*)&Kb[row * 64 + c0 * 8];
      bf16x8 k1 = *(const bf16x8*)&Kb[row * 64 + (c0 ^ 4) * 8];
      f32x4 s = {};
      s = __builtin_amdgcn_mfma_f32_16x16x32_bf16(aq0, k0, s, 0, 0, 0);
      s = __builtin_amdgcn_mfma_f32_16x16x32_bf16(aq1, k1, s, 0, 0, 0);
      st[t] = s;
    }
    if (jg == qg) {
      #pragma unroll
      for (int t = 0; t < 4; ++t)
        #pragma unroll
        for (int r = 0; r < 4; ++r)
          st[t][r] = (16 * t + lr > wid * 16 + 4 * lg + r) ? -1e30f : st[t][r];
    }
    #pragma unroll
    for (int r = 0; r < 4; ++r) {
      float p0 = __builtin_exp2f(st[0][r]);
      float p1 = __builtin_exp2f(st[1][r]);
      float p2 = __builtin_exp2f(st[2][r]);
      float p3 = __builtin_exp2f(st[3][r]);
      lsum[r] += (p0 + p1) + (p2 + p3);
      *(unsigned*)&P[4 * lg + r][2 * lr] = cvt_pk_bf16(p0, p1);
      *(unsigned*)&P[4 * lg + r][32 + 2 * lr] = cvt_pk_bf16(p2, p3);
    }
    asm volatile("s_waitcnt lgkmcnt(0)" ::: "memory");
    __builtin_amdgcn_sched_barrier(0);
    bf16x8 pa0 = *(const bf16x8*)&P[lr][8 * lg];
    bf16x8 pa1 = *(const bf16x8*)&P[lr][32 + 8 * lg];
    #pragma unroll
    for (int nv = 0; nv < 4; ++nv) {
      int row0 = nv * 16 + lr;
      int c0 = lg ^ (row0 & 7);
      bf16x8 v0 = *(const bf16x8*)&Vb[row0 * 64 + c0 * 8];
      bf16x8 v1e = *(const bf16x8*)&Vb[row0 * 64 + (c0 ^ 4) * 8];
      accO[nv] = __builtin_amdgcn_mfma_f32_16x16x32_bf16(pa0, v0, accO[nv], 0, 0, 0);
      accO[nv] = __builtin_amdgcn_mfma_f32_16x16x32_bf16(pa1, v1e, accO[nv], 0, 0, 0);
    }
  }
  short* pO = partO + (size_t)(head * 80 + b) * 4096;
  float* pL = partL + (size_t)(head * 80 + b) * 64;
  #pragma unroll
  for (int r = 0; r < 4; ++r) {
    float sres = lsum[r];
    sres += __shfl_xor(sres, 1);
    sres += __shfl_xor(sres, 2);
    sres += __shfl_xor(sres, 4);
    sres += __shfl_xor(sres, 8);
    int row = wid * 16 + 4 * lg + r;
    #pragma unroll
    for (int nv = 0; nv < 4; ++nv)
      pO[row * 64 + nv * 16 + lr] = f2bs(accO[nv][r]);
    if (lr == 0) pL[row] = sres;
  }
}

// ------- combine split-KV partials, apply gate, write CHUNK-MAJOR bf16 obT[128][2048][8]
__global__ __launch_bounds__(256) void attn_reduce(const short* __restrict__ partO,
                                                   const float* __restrict__ partL,
                                                   const float* __restrict__ gate,
                                                   short* __restrict__ obT) {
  const int head = blockIdx.x & 15;
  const int qg = blockIdx.x >> 4;
  const int ns = (qg >> 3) + 1;
  const int tid = threadIdx.x;
  const int row = tid >> 2, q4 = tid & 3;
  const int sbase[4] = {0, 32, 56, 72};  // strip -> b base (b = sbase[s] + 31 - qg)
  f32x4 o[4] = {};
  float l = 0.f;
  for (int s = 0; s < ns; ++s) {
    const int slot = head * 80 + sbase[s] + 31 - qg;
    const short* pb = partO + (size_t)slot * 4096;
    #pragma unroll
    for (int c = 0; c < 4; ++c) {
      bf16x4 v = *(const bf16x4*)&pb[row * 64 + q4 * 16 + c * 4];
      #pragma unroll
      for (int j = 0; j < 4; ++j) o[c][j] += bs2f(v[j]);
    }
    l += partL[(size_t)slot * 64 + row];
  }
  const int t = qg * 64 + row;
  const float gs = gate[t * 16 + head] / l;
  const int cg0 = head * 8 + q4 * 2;
  bf16x8 w0, w1;
  #pragma unroll
  for (int j = 0; j < 4; ++j) {
    w0[j]     = f2bs(o[0][j] * gs);
    w0[4 + j] = f2bs(o[1][j] * gs);
    w1[j]     = f2bs(o[2][j] * gs);
    w1[4 + j] = f2bs(o[3][j] * gs);
  }
  *(bf16x8*)&obT[((size_t)cg0 * 2048 + t) * 8] = w0;
  *(bf16x8*)&obT[((size_t)(cg0 + 1) * 2048 + t) * 8] = w1;
}

extern "C" void kernel_launch(void* const* d_in, const int* in_sizes, int n_in,
                              void* d_out, int out_size, void* d_ws, size_t ws_size,
                              hipStream_t stream) {
  const float* x     = (const float*)d_in[0];
  const float* v1    = (const float*)d_in[1];
  const float* Wq    = (const float*)d_in[2];
  const float* Wk    = (const float*)d_in[3];
  const float* Wv    = (const float*)d_in[4];
  const float* Wproj = (const float*)d_in[5];
  const float* lamb  = (const float*)d_in[6];
  const float* Wgate = (const float*)d_in[7];
  float* out = (float*)d_out;

  char* ws = (char*)d_ws;
  short*  xbT   = (short*)(ws);                       // 4MB chunk-major x (alias obT)
  short*  wqkvT = (short*)(ws + ((size_t)4  << 20));  // 6MB chunk-major Wq|Wk|Wv
  short*  wpjT  = (short*)(ws + ((size_t)10 << 20));  // 2MB chunk-major Wproj
  short*  partO = (short*)(ws + ((size_t)12 << 20));  // 10.5MB bf16 O partials
  float*  partL = (float*)(ws + ((size_t)23 << 20));  // 327KB f32 lsum partials
  float2* rope  = (float2*)(ws + ((size_t)34 << 20)); // 512KB
  short*  qb    = (short*)(ws + ((size_t)36 << 20));  // 4MB
  short*  kb    = (short*)(ws + ((size_t)40 << 20));  // 4MB
  short*  vt    = (short*)(ws + ((size_t)44 << 20));  // 4MB
  float*  gate  = (float*)(ws + ((size_t)48 << 20));  // 128KB
  short*  obT   = xbT;  // xbT dead after QKV GEMM

  prep<<<dim3(128, 9), 256, 0, stream>>>(x, Wq, Wk, Wv, Wproj, v1, Wgate,
                                         xbT, wqkvT, wpjT,
                                         out + (size_t)T_SEQ * 1024, gate, rope);
  // QKV: 768 blocks = exactly 3/CU uniform (36KB LDS), XCD-chunked (96 tiles/XCD)
  gemm<64, 128, true><<<768, 256, 0, stream>>>(xbT, wqkvT, nullptr, qb, kb, vt,
                                               v1, lamb, rope, 2048, 3072, 1024);
  attn<<<1280, 256, 0, stream>>>(qb, kb, vt, partO, partL);
  attn_reduce<<<512, 256, 0, stream>>>(partO, partL, gate, obT);
  // proj: 512 blocks = 2/CU uniform (24KB LDS), XCD-chunked (64 tiles/XCD)
  gemm<64, 64, false><<<512, 256, 0, stream>>>(obT, wpjT, out, nullptr, nullptr,
                                               nullptr, nullptr, nullptr, nullptr,
                                               2048, 1024, 1024);
}